// Round 22
// baseline (46.758 us; speedup 1.0000x reference)
//
#include <hip/hip_runtime.h>

// LLR denoiser — R22: f32 direct-W apply (no bf16 unpack in matvec) + lean
// zs/apply batch fusion (R19's overlap idea, now viable at 33.3 KB LDS).
//   zs_body:    per patch p, S_p = alpha_p*Zhat_p via register Newton-Schulz
//               (8 patches per 512-thr block, XCD-swizzled).
//   apply_body: quarter strip (4 rows x 128 px = 32 cells). Gather writes
//               FINAL per-cell W in f32 (4 masked zs loads, 1/cnt folded)
//               at pitch 260 (2-way banks = free; R18-verified layout);
//               matvec = 64 broadcast float4 reads + 256 FMA, zero unpack.
//   Launches:   zs8(b0) ; fused{ apply(b0) || zs8(b1) } ; apply(b1).

#define NBATCH  2
#define NCH     16
#define HDIM    512
#define WDIM    512
#define NPH     127
#define NPW     127
#define NPB     (NPH * NPW)            // 16129 patches per batch
#define NCELL   128
#define THS     0.1f
#define NSIT    7

#define ZS8_NBLK ((NPB + 7) / 8)       // 2017 blocks (8 patches each)
#define APQ_NBLK (NCELL * 4)           // 512 quarter-strips per batch

typedef short bf16x8 __attribute__((ext_vector_type(8)));
typedef float f32x4  __attribute__((ext_vector_type(4)));

#define MFMA(a,b,c) __builtin_amdgcn_mfma_f32_16x16x32_bf16((a),(b),(c),0,0,0)

static __device__ inline short f2bf(float x) {
  return __builtin_bit_cast(short, (__bf16)x);   // native RNE convert
}
static __device__ inline float blo2f(unsigned int v) {
  return __builtin_bit_cast(float, v << 16);
}
static __device__ inline float bhi2f(unsigned int v) {
  return __builtin_bit_cast(float, v & 0xffff0000u);
}
static __device__ inline unsigned int pack2bf(float lo, float hi) {
  unsigned int a = (unsigned short)f2bf(lo);
  unsigned int b = (unsigned short)f2bf(hi);
  return (b << 16) | a;
}

// bijective XCD swizzle (m204)
static __device__ inline int xcd_swz(int b, int nwg) {
  const int q = nwg >> 3, r = nwg & 7;
  const int x = b & 7, lo = b >> 3;
  return (x < r ? x * (q + 1) : r * (q + 1) + (x - r) * q) + lo;
}

static __device__ inline bf16x8 fragc(f32x4 v) {
  // symmetric-matrix C-layout -> MFMA A/B fragment (16 nonzero k-slots)
  bf16x8 r;
  r[0] = f2bf(v[0]); r[1] = f2bf(v[1]); r[2] = f2bf(v[2]); r[3] = f2bf(v[3]);
  r[4] = 0; r[5] = 0; r[6] = 0; r[7] = 0;
  return r;
}

// ---------------- zs body: 8 patches per 512-thread block ------------------
static __device__ void zs_body(const float* __restrict__ x,
                               uint2* __restrict__ zs,
                               int zblk, int bi, int t) {
  const int blk = xcd_swz(zblk, ZS8_NBLK);
  const int pr  = blk * 8 + (t >> 6);          // one wave per patch
  if (pr >= NPB) return;
  const int pid = bi * NPB + pr;
  const int ph  = pr / NPW, pw = pr % NPW;
  const int h0  = ph * 4, w0 = pw * 4;
  const int l   = t & 63;
  const int j   = l & 15;
  const int u   = l >> 4;

  const size_t HW = (size_t)HDIM * WDIM;
  const float* xb = x + (size_t)bi * NCH * HW;

  const float* pb = xb + (size_t)j * HW + (size_t)h0 * WDIM + w0;
  const int dh0 = (u >> 1), dw0 = 4 * (u & 1);
  float4 q0 = *(const float4*)(pb + (size_t)(dh0 + 0) * WDIM + dw0);
  float4 q1 = *(const float4*)(pb + (size_t)(dh0 + 2) * WDIM + dw0);
  float4 q2 = *(const float4*)(pb + (size_t)(dh0 + 4) * WDIM + dw0);
  float4 q3 = *(const float4*)(pb + (size_t)(dh0 + 6) * WDIM + dw0);

  bf16x8 m0, m1;
  m0[0]=f2bf(q0.x); m0[1]=f2bf(q0.y); m0[2]=f2bf(q0.z); m0[3]=f2bf(q0.w);
  m0[4]=f2bf(q1.x); m0[5]=f2bf(q1.y); m0[6]=f2bf(q1.z); m0[7]=f2bf(q1.w);
  m1[0]=f2bf(q2.x); m1[1]=f2bf(q2.y); m1[2]=f2bf(q2.z); m1[3]=f2bf(q2.w);
  m1[4]=f2bf(q3.x); m1[5]=f2bf(q3.y); m1[6]=f2bf(q3.z); m1[7]=f2bf(q3.w);

  f32x4 g = {0.f, 0.f, 0.f, 0.f};
  g = MFMA(m0, m0, g);
  g = MFMA(m1, m1, g);

  float s2 = g[0]*g[0] + g[1]*g[1] + g[2]*g[2] + g[3]*g[3];
  #pragma unroll
  for (int m = 32; m >= 1; m >>= 1) s2 += __shfl_xor(s2, m, 64);

  uint2 wv = {0u, 0u};
  if (s2 > 1e-20f) {
    const float invf  = rsqrtf(s2);
    const float gsc   = 2.0f * invf;           // normalize by t = f/2
    const float alpha = THS * sqrtf(gsc);

    f32x4 Yc, Zc;
    #pragma unroll
    for (int r = 0; r < 4; ++r) {
      Yc[r] = g[r] * gsc;
      Zc[r] = (4 * u + r == j) ? 1.0f : 0.0f;
    }

    const f32x4 zero = {0.f, 0.f, 0.f, 0.f};
    for (int it = 0; it < NSIT - 1; ++it) {
      bf16x8 yF = fragc(Yc), zF = fragc(Zc);
      f32x4 tt = MFMA(zF, yF, zero);
      bf16x8 tF = fragc(tt);
      f32x4 py = MFMA(yF, tF, zero);
      f32x4 pz = MFMA(tF, zF, zero);
      #pragma unroll
      for (int r = 0; r < 4; ++r) {
        Yc[r] = 1.5f * Yc[r] - 0.5f * py[r];
        Zc[r] = 1.5f * Zc[r] - 0.5f * pz[r];
      }
    }
    {
      bf16x8 yF = fragc(Yc), zF = fragc(Zc);
      f32x4 tt = MFMA(zF, yF, zero);
      bf16x8 tF = fragc(tt);
      f32x4 pz = MFMA(tF, zF, zero);
      #pragma unroll
      for (int r = 0; r < 4; ++r) Zc[r] = 1.5f * Zc[r] - 0.5f * pz[r];
    }

    wv.x = pack2bf(alpha * Zc[0], alpha * Zc[1]);
    wv.y = pack2bf(alpha * Zc[2], alpha * Zc[3]);
  }
  zs[(size_t)pid * 64 + l] = wv;               // coalesced 512B per patch
}

// ---------------- apply body: quarter strip, f32 direct W ------------------
// abid = ci*4 + qs (within batch bi). 512 threads. PWf pitch 260 f32
// (260c mod 32 = 4c -> 2 cells/bank-window = 2-way = free; 16B-aligned).
// Gather: wave w8 does cells cc = 8*rd + w8; 4 masked coalesced uint2 zs
//   loads, f32 sum, 1/cnt folded; lane (u,j) writes W[4u+e][j], e=0..3.
// Matvec: thread cell c reads 64 broadcast float4, 256 FMA, no unpack.
static __device__ void apply_body(const float* __restrict__ x,
                                  const uint2* __restrict__ zs,
                                  float* __restrict__ out,
                                  float* PWf, int abid, int bi, int t) {
  const int qs  = abid & 3;
  const int ci  = abid >> 2;                   // 0..127
  const int r   = t >> 7;                      // pixel row 0..3
  const int px  = t & 127;                     // pixel col in quarter
  const int c   = px >> 2;                     // cell-local 0..31

  const size_t HW = (size_t)HDIM * WDIM;
  const int h   = 4 * ci + r;
  const int wpx = qs * 128 + px;

  // ---- gather: per-cell f32 W -> LDS (4 cells/wave, 4 masked loads each)
  {
    const int w8 = t >> 6;                     // wave 0..7
    const int l  = t & 63;
    const int u  = l >> 4, j = l & 15;
    const uint2* zb = zs + (size_t)bi * NPB * 64;
    const bool vh0 = (ci > 0), vh1 = (ci < NPH);
    const int ph0c = vh0 ? ci - 1 : 0;
    const int ph1c = vh1 ? ci : NPH - 1;
    const float cnth = 2.0f - (ci == 0) - (ci == NCELL - 1);
    #pragma unroll
    for (int rd = 0; rd < 4; ++rd) {
      const int cc = rd * 8 + w8;              // cell 0..31 (wave-uniform)
      const int cj = qs * 32 + cc;             // global cell col
      const int pwl = cj - 1, pwr = cj;
      const bool vl = (pwl >= 0), vr = (pwr <= NPW - 1);
      const int pwlc = vl ? pwl : 0;
      const int pwrc = vr ? pwr : NPW - 1;
      uint2 z00 = zb[((size_t)ph0c * NPW + pwlc) * 64 + l];
      uint2 z01 = zb[((size_t)ph0c * NPW + pwrc) * 64 + l];
      uint2 z10 = zb[((size_t)ph1c * NPW + pwlc) * 64 + l];
      uint2 z11 = zb[((size_t)ph1c * NPW + pwrc) * 64 + l];
      if (!(vh0 && vl)) { z00.x = 0u; z00.y = 0u; }
      if (!(vh0 && vr)) { z01.x = 0u; z01.y = 0u; }
      if (!(vh1 && vl)) { z10.x = 0u; z10.y = 0u; }
      if (!(vh1 && vr)) { z11.x = 0u; z11.y = 0u; }

      const float cntw = 2.0f - (cj == 0) - (cj == NCELL - 1);
      const float sc = 1.0f / (cnth * cntw);
      float* wb = &PWf[cc * 260 + j];
      wb[16 * (4 * u + 0)] = sc * (blo2f(z00.x) + blo2f(z01.x) + blo2f(z10.x) + blo2f(z11.x));
      wb[16 * (4 * u + 1)] = sc * (bhi2f(z00.x) + bhi2f(z01.x) + bhi2f(z10.x) + bhi2f(z11.x));
      wb[16 * (4 * u + 2)] = sc * (blo2f(z00.y) + blo2f(z01.y) + blo2f(z10.y) + blo2f(z11.y));
      wb[16 * (4 * u + 3)] = sc * (bhi2f(z00.y) + bhi2f(z01.y) + bhi2f(z10.y) + bhi2f(z11.y));
    }
  }
  __syncthreads();

  // ---- phase B: x loads (after barrier), matvec: 64 broadcast float4 reads
  const float* xp = x + (size_t)bi * NCH * HW + (size_t)h * WDIM + wpx;
  float xv[16];
  #pragma unroll
  for (int e = 0; e < 16; ++e) xv[e] = xp[(size_t)e * HW];

  const float* wb = &PWf[c * 260];
  float* po = out + (size_t)bi * NCH * HW + (size_t)h * WDIM + wpx;
  #pragma unroll
  for (int co = 0; co < 16; ++co) {
    float acc = 0.f;
    #pragma unroll
    for (int k = 0; k < 4; ++k) {
      const float4 W4 = *(const float4*)(wb + 16 * co + 4 * k);  // broadcast x4
      acc += W4.x * xv[4 * k + 0];
      acc += W4.y * xv[4 * k + 1];
      acc += W4.z * xv[4 * k + 2];
      acc += W4.w * xv[4 * k + 3];
    }
    po[(size_t)co * HW] = xv[co] - acc;        // scale pre-folded into W
  }
}

// ---------------- kernels ---------------------------------------------------
__global__ __launch_bounds__(512, 8) void llr_zs8(const float* __restrict__ x,
                                                  uint2* __restrict__ zs,
                                                  int bi) {
  zs_body(x, zs, blockIdx.x, bi, threadIdx.x);
}

__global__ __launch_bounds__(512, 8) void llr_ap(const float* __restrict__ x,
                                                 const uint2* __restrict__ zs,
                                                 float* __restrict__ out,
                                                 int bi) {
  __shared__ float PWf[32 * 260];              // 33.3 KB
  apply_body(x, zs, out, PWf, blockIdx.x, bi, threadIdx.x);
}

// fused: blocks [0, APQ_NBLK) = apply(batch0); rest = zs(batch1).
// zs(b1) writes a disjoint zs region; apply(b0) reads zs(b0) completed by
// the previous kernel. 33.3 KB LDS -> 4 blocks/CU for both roles.
__global__ __launch_bounds__(512, 8) void llr_fused(const float* __restrict__ x,
                                                    uint2* __restrict__ zs,
                                                    float* __restrict__ out) {
  __shared__ float PWf[32 * 260];
  const int bid = blockIdx.x;
  if (bid < APQ_NBLK) {
    apply_body(x, zs, out, PWf, bid, 0, threadIdx.x);
  } else {
    zs_body(x, zs, bid - APQ_NBLK, 1, threadIdx.x);
  }
}

extern "C" void kernel_launch(void* const* d_in, const int* in_sizes, int n_in,
                              void* d_out, int out_size, void* d_ws, size_t ws_size,
                              hipStream_t stream) {
  const float* x = (const float*)d_in[0];
  float* out = (float*)d_out;
  uint2* zs = (uint2*)d_ws;                    // 32258*512B = 16.5 MB

  llr_zs8<<<dim3(ZS8_NBLK), dim3(512), 0, stream>>>(x, zs, 0);
  llr_fused<<<dim3(APQ_NBLK + ZS8_NBLK), dim3(512), 0, stream>>>(x, zs, out);
  llr_ap<<<dim3(APQ_NBLK), dim3(512), 0, stream>>>(x, zs, out, 1);
}

// Round 23
// 43.709 us; speedup vs baseline: 1.0697x; 1.0697x over previous
//
#include <hip/hip_runtime.h>

// LLR denoiser, two-phase, atomic-free (R23 = R21 structure + f32 direct-W):
//   Phase 1 (llr_zs): per patch p, S_p = alpha_p * Zhat_p (16x16 ~ THS*G^{-1/2})
//            via register-resident Newton-Schulz; bf16 to ws. XCD-swizzled,
//            4 waves/block, NSIT 7.
//   Phase 2 (llr_ap): quarter-strip (4 rows x 128 px = 32 cells), 512 thr.
//            Gather writes FINAL per-cell W in f32 (4 masked zs loads,
//            1/cnt folded) at pitch 260 (2-way banks = free); matvec = 64
//            broadcast float4 reads + 256 FMA, zero unpack; x loads after
//            the barrier. 33.3 KB LDS -> 4 blocks/CU. Two launches only.

#define NBATCH  2
#define NCH     16
#define HDIM    512
#define WDIM    512
#define NPH     127
#define NPW     127
#define NPATCH  (NBATCH * NPH * NPW)
#define NCELL   128
#define THS     0.1f
#define NSIT    7

typedef short bf16x8 __attribute__((ext_vector_type(8)));
typedef float f32x4  __attribute__((ext_vector_type(4)));

#define MFMA(a,b,c) __builtin_amdgcn_mfma_f32_16x16x32_bf16((a),(b),(c),0,0,0)

static __device__ inline short f2bf(float x) {
  return __builtin_bit_cast(short, (__bf16)x);   // native RNE convert
}
static __device__ inline float blo2f(unsigned int v) {
  return __builtin_bit_cast(float, v << 16);
}
static __device__ inline float bhi2f(unsigned int v) {
  return __builtin_bit_cast(float, v & 0xffff0000u);
}
static __device__ inline unsigned int pack2bf(float lo, float hi) {
  unsigned int a = (unsigned short)f2bf(lo);
  unsigned int b = (unsigned short)f2bf(hi);
  return (b << 16) | a;
}

// bijective XCD swizzle (m204) — used by llr_zs only
static __device__ inline int xcd_swz(int b, int nwg) {
  const int q = nwg >> 3, r = nwg & 7;
  const int x = b & 7, lo = b >> 3;
  return (x < r ? x * (q + 1) : r * (q + 1) + (x - r) * q) + lo;
}

static __device__ inline bf16x8 fragc(f32x4 v) {
  // symmetric-matrix C-layout -> MFMA A/B fragment (16 nonzero k-slots)
  bf16x8 r;
  r[0] = f2bf(v[0]); r[1] = f2bf(v[1]); r[2] = f2bf(v[2]); r[3] = f2bf(v[3]);
  r[4] = 0; r[5] = 0; r[6] = 0; r[7] = 0;
  return r;
}

// ---------------- Phase 1: per-patch scaled inverse-sqrt matrices ----------
#define ZS_NBLK ((NPATCH + 3) / 4)
__global__ __launch_bounds__(256) void llr_zs(const float* __restrict__ x,
                                              uint2* __restrict__ zs) {
  const int blk = xcd_swz(blockIdx.x, ZS_NBLK);
  const int pid = blk * 4 + (threadIdx.x >> 6);  // one wave per patch
  if (pid >= NPATCH) return;
  const int bi  = pid / (NPH * NPW);
  const int pr  = pid % (NPH * NPW);
  const int ph  = pr / NPW, pw = pr % NPW;
  const int h0  = ph * 4, w0 = pw * 4;
  const int l   = threadIdx.x & 63;
  const int j   = l & 15;
  const int u   = l >> 4;

  const size_t HW = (size_t)HDIM * WDIM;
  const float* xb = x + (size_t)bi * NCH * HW;

  const float* pb = xb + (size_t)j * HW + (size_t)h0 * WDIM + w0;
  const int dh0 = (u >> 1), dw0 = 4 * (u & 1);
  float4 q0 = *(const float4*)(pb + (size_t)(dh0 + 0) * WDIM + dw0);
  float4 q1 = *(const float4*)(pb + (size_t)(dh0 + 2) * WDIM + dw0);
  float4 q2 = *(const float4*)(pb + (size_t)(dh0 + 4) * WDIM + dw0);
  float4 q3 = *(const float4*)(pb + (size_t)(dh0 + 6) * WDIM + dw0);

  bf16x8 m0, m1;
  m0[0]=f2bf(q0.x); m0[1]=f2bf(q0.y); m0[2]=f2bf(q0.z); m0[3]=f2bf(q0.w);
  m0[4]=f2bf(q1.x); m0[5]=f2bf(q1.y); m0[6]=f2bf(q1.z); m0[7]=f2bf(q1.w);
  m1[0]=f2bf(q2.x); m1[1]=f2bf(q2.y); m1[2]=f2bf(q2.z); m1[3]=f2bf(q2.w);
  m1[4]=f2bf(q3.x); m1[5]=f2bf(q3.y); m1[6]=f2bf(q3.z); m1[7]=f2bf(q3.w);

  f32x4 g = {0.f, 0.f, 0.f, 0.f};
  g = MFMA(m0, m0, g);
  g = MFMA(m1, m1, g);

  float s2 = g[0]*g[0] + g[1]*g[1] + g[2]*g[2] + g[3]*g[3];
  #pragma unroll
  for (int m = 32; m >= 1; m >>= 1) s2 += __shfl_xor(s2, m, 64);

  uint2 wv = {0u, 0u};
  if (s2 > 1e-20f) {
    const float invf  = rsqrtf(s2);
    const float gsc   = 2.0f * invf;           // normalize by t = f/2
    const float alpha = THS * sqrtf(gsc);

    f32x4 Yc, Zc;
    #pragma unroll
    for (int r = 0; r < 4; ++r) {
      Yc[r] = g[r] * gsc;
      Zc[r] = (4 * u + r == j) ? 1.0f : 0.0f;
    }

    const f32x4 zero = {0.f, 0.f, 0.f, 0.f};
    for (int it = 0; it < NSIT - 1; ++it) {
      bf16x8 yF = fragc(Yc), zF = fragc(Zc);
      f32x4 t  = MFMA(zF, yF, zero);
      bf16x8 tF = fragc(t);
      f32x4 py = MFMA(yF, tF, zero);
      f32x4 pz = MFMA(tF, zF, zero);
      #pragma unroll
      for (int r = 0; r < 4; ++r) {
        Yc[r] = 1.5f * Yc[r] - 0.5f * py[r];
        Zc[r] = 1.5f * Zc[r] - 0.5f * pz[r];
      }
    }
    {
      bf16x8 yF = fragc(Yc), zF = fragc(Zc);
      f32x4 t  = MFMA(zF, yF, zero);
      bf16x8 tF = fragc(t);
      f32x4 pz = MFMA(tF, zF, zero);
      #pragma unroll
      for (int r = 0; r < 4; ++r) Zc[r] = 1.5f * Zc[r] - 0.5f * pz[r];
    }

    wv.x = pack2bf(alpha * Zc[0], alpha * Zc[1]);
    wv.y = pack2bf(alpha * Zc[2], alpha * Zc[3]);
  }
  zs[(size_t)pid * 64 + l] = wv;
}

// ---------------- Phase 2: quarter-strip apply, f32 direct W ---------------
// Block = (bi, ci, qs): 4 rows x 128 px = 32 cells. 512 threads.
// PWf pitch 260 f32: banks 4c mod 32, 4-lane broadcast per cell -> 2-way.
// Gather: wave w8 does cells cc = 8*rd + w8; 4 masked coalesced uint2 zs
//   loads, f32 sum, 1/cnt folded; lane (u,j) writes W[4u+e][j], e=0..3.
// Matvec: thread cell c reads 64 broadcast float4, 256 FMA, no unpack.
#define Q_NBLK (NBATCH * NCELL * 4)   // 1024 -> 4 blocks/CU
__global__ __launch_bounds__(512, 8) void llr_ap(const float* __restrict__ x,
                                                 const uint2* __restrict__ zs,
                                                 float* __restrict__ out) {
  __shared__ float PWf[32 * 260];              // 33.3 KB

  const int bid = blockIdx.x;                  // bi*512 + ci*4 + qs
  const int qs  = bid & 3;
  const int ci  = (bid >> 2) & 127;
  const int bi  = bid >> 9;
  const int t   = threadIdx.x;
  const int r   = t >> 7;                      // pixel row 0..3
  const int px  = t & 127;                     // pixel col in quarter
  const int c   = px >> 2;                     // cell-local 0..31

  const size_t HW = (size_t)HDIM * WDIM;
  const int h   = 4 * ci + r;
  const int wpx = qs * 128 + px;

  // ---- gather: per-cell f32 W -> LDS (4 cells/wave, 4 masked loads each)
  {
    const int w8 = t >> 6;                     // wave 0..7
    const int l  = t & 63;
    const int u  = l >> 4, j = l & 15;
    const uint2* zb = zs + (size_t)bi * NPH * NPW * 64;
    const bool vh0 = (ci > 0), vh1 = (ci < NPH);
    const int ph0c = vh0 ? ci - 1 : 0;
    const int ph1c = vh1 ? ci : NPH - 1;
    const float cnth = 2.0f - (ci == 0) - (ci == NCELL - 1);
    #pragma unroll
    for (int rd = 0; rd < 4; ++rd) {
      const int cc = rd * 8 + w8;              // cell 0..31 (wave-uniform)
      const int cj = qs * 32 + cc;             // global cell col
      const int pwl = cj - 1, pwr = cj;
      const bool vl = (pwl >= 0), vr = (pwr <= NPW - 1);
      const int pwlc = vl ? pwl : 0;
      const int pwrc = vr ? pwr : NPW - 1;
      uint2 z00 = zb[((size_t)ph0c * NPW + pwlc) * 64 + l];
      uint2 z01 = zb[((size_t)ph0c * NPW + pwrc) * 64 + l];
      uint2 z10 = zb[((size_t)ph1c * NPW + pwlc) * 64 + l];
      uint2 z11 = zb[((size_t)ph1c * NPW + pwrc) * 64 + l];
      if (!(vh0 && vl)) { z00.x = 0u; z00.y = 0u; }
      if (!(vh0 && vr)) { z01.x = 0u; z01.y = 0u; }
      if (!(vh1 && vl)) { z10.x = 0u; z10.y = 0u; }
      if (!(vh1 && vr)) { z11.x = 0u; z11.y = 0u; }

      const float cntw = 2.0f - (cj == 0) - (cj == NCELL - 1);
      const float sc = 1.0f / (cnth * cntw);
      float* wb = &PWf[cc * 260 + j];
      wb[16 * (4 * u + 0)] = sc * (blo2f(z00.x) + blo2f(z01.x) + blo2f(z10.x) + blo2f(z11.x));
      wb[16 * (4 * u + 1)] = sc * (bhi2f(z00.x) + bhi2f(z01.x) + bhi2f(z10.x) + bhi2f(z11.x));
      wb[16 * (4 * u + 2)] = sc * (blo2f(z00.y) + blo2f(z01.y) + blo2f(z10.y) + blo2f(z11.y));
      wb[16 * (4 * u + 3)] = sc * (bhi2f(z00.y) + bhi2f(z01.y) + bhi2f(z10.y) + bhi2f(z11.y));
    }
  }
  __syncthreads();

  // ---- phase B: x loads (after barrier), matvec: 64 broadcast float4 reads
  const float* xp = x + (size_t)bi * NCH * HW + (size_t)h * WDIM + wpx;
  float xv[16];
  #pragma unroll
  for (int e = 0; e < 16; ++e) xv[e] = xp[(size_t)e * HW];

  const float* wb = &PWf[c * 260];
  float* po = out + (size_t)bi * NCH * HW + (size_t)h * WDIM + wpx;
  #pragma unroll
  for (int co = 0; co < 16; ++co) {
    float acc = 0.f;
    #pragma unroll
    for (int k = 0; k < 4; ++k) {
      const float4 W4 = *(const float4*)(wb + 16 * co + 4 * k);  // broadcast x4
      acc += W4.x * xv[4 * k + 0];
      acc += W4.y * xv[4 * k + 1];
      acc += W4.z * xv[4 * k + 2];
      acc += W4.w * xv[4 * k + 3];
    }
    po[(size_t)co * HW] = xv[co] - acc;        // scale pre-folded into W
  }
}

extern "C" void kernel_launch(void* const* d_in, const int* in_sizes, int n_in,
                              void* d_out, int out_size, void* d_ws, size_t ws_size,
                              hipStream_t stream) {
  const float* x = (const float*)d_in[0];
  float* out = (float*)d_out;
  uint2* zs = (uint2*)d_ws;                    // 32258*512B = 16.5 MB

  llr_zs<<<dim3(ZS_NBLK), dim3(256), 0, stream>>>(x, zs);
  llr_ap<<<dim3(Q_NBLK), dim3(512), 0, stream>>>(x, zs, out);
}

// Round 24
// 42.898 us; speedup vs baseline: 1.0900x; 1.0189x over previous
//
#include <hip/hip_runtime.h>

// LLR denoiser, two-phase, atomic-free (R24 = R23 apply at octant granularity):
//   Phase 1 (llr_zs): per patch p, S_p = alpha_p * Zhat_p (16x16 ~ THS*G^{-1/2})
//            via register-resident Newton-Schulz; bf16 to ws. XCD-swizzled.
//   Phase 2 (llr_ap): octant (4 rows x 64 px = 16 cells), 256 thr.
//            Halved block vs R23: per-block serial chain T_b halves and
//            8 blocks/CU (32 waves) overlap gather/barrier/matvec phases
//            across blocks; dispatch tail (last wavefront of blocks with
//            nothing to overlap) also halves. Same per-pixel work: f32
//            direct-W gather (4 masked zs loads/cell, 1/cnt folded),
//            broadcast float4 matvec, x loads after the barrier.

#define NBATCH  2
#define NCH     16
#define HDIM    512
#define WDIM    512
#define NPH     127
#define NPW     127
#define NPATCH  (NBATCH * NPH * NPW)
#define NCELL   128
#define THS     0.1f
#define NSIT    7

typedef short bf16x8 __attribute__((ext_vector_type(8)));
typedef float f32x4  __attribute__((ext_vector_type(4)));

#define MFMA(a,b,c) __builtin_amdgcn_mfma_f32_16x16x32_bf16((a),(b),(c),0,0,0)

static __device__ inline short f2bf(float x) {
  return __builtin_bit_cast(short, (__bf16)x);   // native RNE convert
}
static __device__ inline float blo2f(unsigned int v) {
  return __builtin_bit_cast(float, v << 16);
}
static __device__ inline float bhi2f(unsigned int v) {
  return __builtin_bit_cast(float, v & 0xffff0000u);
}
static __device__ inline unsigned int pack2bf(float lo, float hi) {
  unsigned int a = (unsigned short)f2bf(lo);
  unsigned int b = (unsigned short)f2bf(hi);
  return (b << 16) | a;
}

// bijective XCD swizzle (m204) — used by llr_zs only
static __device__ inline int xcd_swz(int b, int nwg) {
  const int q = nwg >> 3, r = nwg & 7;
  const int x = b & 7, lo = b >> 3;
  return (x < r ? x * (q + 1) : r * (q + 1) + (x - r) * q) + lo;
}

static __device__ inline bf16x8 fragc(f32x4 v) {
  // symmetric-matrix C-layout -> MFMA A/B fragment (16 nonzero k-slots)
  bf16x8 r;
  r[0] = f2bf(v[0]); r[1] = f2bf(v[1]); r[2] = f2bf(v[2]); r[3] = f2bf(v[3]);
  r[4] = 0; r[5] = 0; r[6] = 0; r[7] = 0;
  return r;
}

// ---------------- Phase 1: per-patch scaled inverse-sqrt matrices ----------
#define ZS_NBLK ((NPATCH + 3) / 4)
__global__ __launch_bounds__(256) void llr_zs(const float* __restrict__ x,
                                              uint2* __restrict__ zs) {
  const int blk = xcd_swz(blockIdx.x, ZS_NBLK);
  const int pid = blk * 4 + (threadIdx.x >> 6);  // one wave per patch
  if (pid >= NPATCH) return;
  const int bi  = pid / (NPH * NPW);
  const int pr  = pid % (NPH * NPW);
  const int ph  = pr / NPW, pw = pr % NPW;
  const int h0  = ph * 4, w0 = pw * 4;
  const int l   = threadIdx.x & 63;
  const int j   = l & 15;
  const int u   = l >> 4;

  const size_t HW = (size_t)HDIM * WDIM;
  const float* xb = x + (size_t)bi * NCH * HW;

  const float* pb = xb + (size_t)j * HW + (size_t)h0 * WDIM + w0;
  const int dh0 = (u >> 1), dw0 = 4 * (u & 1);
  float4 q0 = *(const float4*)(pb + (size_t)(dh0 + 0) * WDIM + dw0);
  float4 q1 = *(const float4*)(pb + (size_t)(dh0 + 2) * WDIM + dw0);
  float4 q2 = *(const float4*)(pb + (size_t)(dh0 + 4) * WDIM + dw0);
  float4 q3 = *(const float4*)(pb + (size_t)(dh0 + 6) * WDIM + dw0);

  bf16x8 m0, m1;
  m0[0]=f2bf(q0.x); m0[1]=f2bf(q0.y); m0[2]=f2bf(q0.z); m0[3]=f2bf(q0.w);
  m0[4]=f2bf(q1.x); m0[5]=f2bf(q1.y); m0[6]=f2bf(q1.z); m0[7]=f2bf(q1.w);
  m1[0]=f2bf(q2.x); m1[1]=f2bf(q2.y); m1[2]=f2bf(q2.z); m1[3]=f2bf(q2.w);
  m1[4]=f2bf(q3.x); m1[5]=f2bf(q3.y); m1[6]=f2bf(q3.z); m1[7]=f2bf(q3.w);

  f32x4 g = {0.f, 0.f, 0.f, 0.f};
  g = MFMA(m0, m0, g);
  g = MFMA(m1, m1, g);

  float s2 = g[0]*g[0] + g[1]*g[1] + g[2]*g[2] + g[3]*g[3];
  #pragma unroll
  for (int m = 32; m >= 1; m >>= 1) s2 += __shfl_xor(s2, m, 64);

  uint2 wv = {0u, 0u};
  if (s2 > 1e-20f) {
    const float invf  = rsqrtf(s2);
    const float gsc   = 2.0f * invf;           // normalize by t = f/2
    const float alpha = THS * sqrtf(gsc);

    f32x4 Yc, Zc;
    #pragma unroll
    for (int r = 0; r < 4; ++r) {
      Yc[r] = g[r] * gsc;
      Zc[r] = (4 * u + r == j) ? 1.0f : 0.0f;
    }

    const f32x4 zero = {0.f, 0.f, 0.f, 0.f};
    for (int it = 0; it < NSIT - 1; ++it) {
      bf16x8 yF = fragc(Yc), zF = fragc(Zc);
      f32x4 t  = MFMA(zF, yF, zero);
      bf16x8 tF = fragc(t);
      f32x4 py = MFMA(yF, tF, zero);
      f32x4 pz = MFMA(tF, zF, zero);
      #pragma unroll
      for (int r = 0; r < 4; ++r) {
        Yc[r] = 1.5f * Yc[r] - 0.5f * py[r];
        Zc[r] = 1.5f * Zc[r] - 0.5f * pz[r];
      }
    }
    {
      bf16x8 yF = fragc(Yc), zF = fragc(Zc);
      f32x4 t  = MFMA(zF, yF, zero);
      bf16x8 tF = fragc(t);
      f32x4 pz = MFMA(tF, zF, zero);
      #pragma unroll
      for (int r = 0; r < 4; ++r) Zc[r] = 1.5f * Zc[r] - 0.5f * pz[r];
    }

    wv.x = pack2bf(alpha * Zc[0], alpha * Zc[1]);
    wv.y = pack2bf(alpha * Zc[2], alpha * Zc[3]);
  }
  zs[(size_t)pid * 64 + l] = wv;
}

// ---------------- Phase 2: octant apply, f32 direct W ----------------------
// Block = (bi, ci, oc): 4 rows x 64 px = 16 cells. 256 threads, 4 waves.
//   thread t: r = t>>6 (pixel row), px = t&63, cell c = px>>2.
// Gather: wave w4 = t>>6 does cells cc = 4*rd + w4 (4 rounds); per cell
//   4 masked coalesced uint2 zs loads, f32 sum, 1/cnt folded; lane (u,j)
//   writes W[4u+e][j], e=0..3, at pitch 260 f32 (banks 4c%32, 4-lane
//   broadcast per cell -> 2-way = free). 16.6 KB LDS -> 8 blocks/CU.
// Matvec: thread cell c reads 64 broadcast float4, 256 FMA, no unpack.
#define Q_NBLK (NBATCH * NCELL * 8)   // 2048 -> 8 blocks/CU
__global__ __launch_bounds__(256, 8) void llr_ap(const float* __restrict__ x,
                                                 const uint2* __restrict__ zs,
                                                 float* __restrict__ out) {
  __shared__ float PWf[16 * 260];              // 16.6 KB

  const int bid = blockIdx.x;                  // bi*1024 + ci*8 + oc
  const int oc  = bid & 7;
  const int ci  = (bid >> 3) & 127;
  const int bi  = bid >> 10;
  const int t   = threadIdx.x;
  const int r   = t >> 6;                      // pixel row 0..3 (= wave id)
  const int px  = t & 63;                      // pixel col in octant
  const int c   = px >> 2;                     // cell-local 0..15

  const size_t HW = (size_t)HDIM * WDIM;
  const int h   = 4 * ci + r;
  const int wpx = oc * 64 + px;

  // ---- gather: per-cell f32 W -> LDS (4 cells/wave, 4 masked loads each)
  {
    const int w4 = t >> 6;                     // wave 0..3
    const int l  = t & 63;
    const int u  = l >> 4, j = l & 15;
    const uint2* zb = zs + (size_t)bi * NPH * NPW * 64;
    const bool vh0 = (ci > 0), vh1 = (ci < NPH);
    const int ph0c = vh0 ? ci - 1 : 0;
    const int ph1c = vh1 ? ci : NPH - 1;
    const float cnth = 2.0f - (ci == 0) - (ci == NCELL - 1);
    #pragma unroll
    for (int rd = 0; rd < 4; ++rd) {
      const int cc = rd * 4 + w4;              // cell 0..15 (wave-uniform)
      const int cj = oc * 16 + cc;             // global cell col
      const int pwl = cj - 1, pwr = cj;
      const bool vl = (pwl >= 0), vr = (pwr <= NPW - 1);
      const int pwlc = vl ? pwl : 0;
      const int pwrc = vr ? pwr : NPW - 1;
      uint2 z00 = zb[((size_t)ph0c * NPW + pwlc) * 64 + l];
      uint2 z01 = zb[((size_t)ph0c * NPW + pwrc) * 64 + l];
      uint2 z10 = zb[((size_t)ph1c * NPW + pwlc) * 64 + l];
      uint2 z11 = zb[((size_t)ph1c * NPW + pwrc) * 64 + l];
      if (!(vh0 && vl)) { z00.x = 0u; z00.y = 0u; }
      if (!(vh0 && vr)) { z01.x = 0u; z01.y = 0u; }
      if (!(vh1 && vl)) { z10.x = 0u; z10.y = 0u; }
      if (!(vh1 && vr)) { z11.x = 0u; z11.y = 0u; }

      const float cntw = 2.0f - (cj == 0) - (cj == NCELL - 1);
      const float sc = 1.0f / (cnth * cntw);
      float* wb = &PWf[cc * 260 + j];
      wb[16 * (4 * u + 0)] = sc * (blo2f(z00.x) + blo2f(z01.x) + blo2f(z10.x) + blo2f(z11.x));
      wb[16 * (4 * u + 1)] = sc * (bhi2f(z00.x) + bhi2f(z01.x) + bhi2f(z10.x) + bhi2f(z11.x));
      wb[16 * (4 * u + 2)] = sc * (blo2f(z00.y) + blo2f(z01.y) + blo2f(z10.y) + blo2f(z11.y));
      wb[16 * (4 * u + 3)] = sc * (bhi2f(z00.y) + bhi2f(z01.y) + bhi2f(z10.y) + bhi2f(z11.y));
    }
  }
  __syncthreads();

  // ---- phase B: x loads (after barrier), matvec: 64 broadcast float4 reads
  const float* xp = x + (size_t)bi * NCH * HW + (size_t)h * WDIM + wpx;
  float xv[16];
  #pragma unroll
  for (int e = 0; e < 16; ++e) xv[e] = xp[(size_t)e * HW];

  const float* wb = &PWf[c * 260];
  float* po = out + (size_t)bi * NCH * HW + (size_t)h * WDIM + wpx;
  #pragma unroll
  for (int co = 0; co < 16; ++co) {
    float acc = 0.f;
    #pragma unroll
    for (int k = 0; k < 4; ++k) {
      const float4 W4 = *(const float4*)(wb + 16 * co + 4 * k);  // broadcast x4
      acc += W4.x * xv[4 * k + 0];
      acc += W4.y * xv[4 * k + 1];
      acc += W4.z * xv[4 * k + 2];
      acc += W4.w * xv[4 * k + 3];
    }
    po[(size_t)co * HW] = xv[co] - acc;        // scale pre-folded into W
  }
}

extern "C" void kernel_launch(void* const* d_in, const int* in_sizes, int n_in,
                              void* d_out, int out_size, void* d_ws, size_t ws_size,
                              hipStream_t stream) {
  const float* x = (const float*)d_in[0];
  float* out = (float*)d_out;
  uint2* zs = (uint2*)d_ws;                    // 32258*512B = 16.5 MB

  llr_zs<<<dim3(ZS_NBLK), dim3(256), 0, stream>>>(x, zs);
  llr_ap<<<dim3(Q_NBLK), dim3(256), 0, stream>>>(x, zs, out);
}

// Round 25
// 41.827 us; speedup vs baseline: 1.1179x; 1.0256x over previous
//
#include <hip/hip_runtime.h>

// LLR denoiser, two-phase, atomic-free (R25 = R24 + NSIT 6):
//   Phase 1 (llr_zs): per patch p, S_p = alpha_p * Zhat_p (16x16 ~ THS*G^{-1/2})
//            via register-resident Newton-Schulz; bf16 to ws. XCD-swizzled.
//            NSIT 6: worst-case lam/t ~= 0.084 -> 1-4e-5 after 6 maps;
//            error far below the bf16 rounding floor (absmax 0.0156).
//   Phase 2 (llr_ap): octant (4 rows x 64 px = 16 cells), 256 thr,
//            8 blocks/CU. f32 direct-W gather (4 masked zs loads/cell,
//            1/cnt folded), broadcast float4 matvec, x loads after barrier.

#define NBATCH  2
#define NCH     16
#define HDIM    512
#define WDIM    512
#define NPH     127
#define NPW     127
#define NPATCH  (NBATCH * NPH * NPW)
#define NCELL   128
#define THS     0.1f
#define NSIT    6

typedef short bf16x8 __attribute__((ext_vector_type(8)));
typedef float f32x4  __attribute__((ext_vector_type(4)));

#define MFMA(a,b,c) __builtin_amdgcn_mfma_f32_16x16x32_bf16((a),(b),(c),0,0,0)

static __device__ inline short f2bf(float x) {
  return __builtin_bit_cast(short, (__bf16)x);   // native RNE convert
}
static __device__ inline float blo2f(unsigned int v) {
  return __builtin_bit_cast(float, v << 16);
}
static __device__ inline float bhi2f(unsigned int v) {
  return __builtin_bit_cast(float, v & 0xffff0000u);
}
static __device__ inline unsigned int pack2bf(float lo, float hi) {
  unsigned int a = (unsigned short)f2bf(lo);
  unsigned int b = (unsigned short)f2bf(hi);
  return (b << 16) | a;
}

// bijective XCD swizzle (m204) — used by llr_zs only
static __device__ inline int xcd_swz(int b, int nwg) {
  const int q = nwg >> 3, r = nwg & 7;
  const int x = b & 7, lo = b >> 3;
  return (x < r ? x * (q + 1) : r * (q + 1) + (x - r) * q) + lo;
}

static __device__ inline bf16x8 fragc(f32x4 v) {
  // symmetric-matrix C-layout -> MFMA A/B fragment (16 nonzero k-slots)
  bf16x8 r;
  r[0] = f2bf(v[0]); r[1] = f2bf(v[1]); r[2] = f2bf(v[2]); r[3] = f2bf(v[3]);
  r[4] = 0; r[5] = 0; r[6] = 0; r[7] = 0;
  return r;
}

// ---------------- Phase 1: per-patch scaled inverse-sqrt matrices ----------
#define ZS_NBLK ((NPATCH + 3) / 4)
__global__ __launch_bounds__(256) void llr_zs(const float* __restrict__ x,
                                              uint2* __restrict__ zs) {
  const int blk = xcd_swz(blockIdx.x, ZS_NBLK);
  const int pid = blk * 4 + (threadIdx.x >> 6);  // one wave per patch
  if (pid >= NPATCH) return;
  const int bi  = pid / (NPH * NPW);
  const int pr  = pid % (NPH * NPW);
  const int ph  = pr / NPW, pw = pr % NPW;
  const int h0  = ph * 4, w0 = pw * 4;
  const int l   = threadIdx.x & 63;
  const int j   = l & 15;
  const int u   = l >> 4;

  const size_t HW = (size_t)HDIM * WDIM;
  const float* xb = x + (size_t)bi * NCH * HW;

  const float* pb = xb + (size_t)j * HW + (size_t)h0 * WDIM + w0;
  const int dh0 = (u >> 1), dw0 = 4 * (u & 1);
  float4 q0 = *(const float4*)(pb + (size_t)(dh0 + 0) * WDIM + dw0);
  float4 q1 = *(const float4*)(pb + (size_t)(dh0 + 2) * WDIM + dw0);
  float4 q2 = *(const float4*)(pb + (size_t)(dh0 + 4) * WDIM + dw0);
  float4 q3 = *(const float4*)(pb + (size_t)(dh0 + 6) * WDIM + dw0);

  bf16x8 m0, m1;
  m0[0]=f2bf(q0.x); m0[1]=f2bf(q0.y); m0[2]=f2bf(q0.z); m0[3]=f2bf(q0.w);
  m0[4]=f2bf(q1.x); m0[5]=f2bf(q1.y); m0[6]=f2bf(q1.z); m0[7]=f2bf(q1.w);
  m1[0]=f2bf(q2.x); m1[1]=f2bf(q2.y); m1[2]=f2bf(q2.z); m1[3]=f2bf(q2.w);
  m1[4]=f2bf(q3.x); m1[5]=f2bf(q3.y); m1[6]=f2bf(q3.z); m1[7]=f2bf(q3.w);

  f32x4 g = {0.f, 0.f, 0.f, 0.f};
  g = MFMA(m0, m0, g);
  g = MFMA(m1, m1, g);

  float s2 = g[0]*g[0] + g[1]*g[1] + g[2]*g[2] + g[3]*g[3];
  #pragma unroll
  for (int m = 32; m >= 1; m >>= 1) s2 += __shfl_xor(s2, m, 64);

  uint2 wv = {0u, 0u};
  if (s2 > 1e-20f) {
    const float invf  = rsqrtf(s2);
    const float gsc   = 2.0f * invf;           // normalize by t = f/2
    const float alpha = THS * sqrtf(gsc);

    f32x4 Yc, Zc;
    #pragma unroll
    for (int r = 0; r < 4; ++r) {
      Yc[r] = g[r] * gsc;
      Zc[r] = (4 * u + r == j) ? 1.0f : 0.0f;
    }

    const f32x4 zero = {0.f, 0.f, 0.f, 0.f};
    for (int it = 0; it < NSIT - 1; ++it) {
      bf16x8 yF = fragc(Yc), zF = fragc(Zc);
      f32x4 t  = MFMA(zF, yF, zero);
      bf16x8 tF = fragc(t);
      f32x4 py = MFMA(yF, tF, zero);
      f32x4 pz = MFMA(tF, zF, zero);
      #pragma unroll
      for (int r = 0; r < 4; ++r) {
        Yc[r] = 1.5f * Yc[r] - 0.5f * py[r];
        Zc[r] = 1.5f * Zc[r] - 0.5f * pz[r];
      }
    }
    {
      bf16x8 yF = fragc(Yc), zF = fragc(Zc);
      f32x4 t  = MFMA(zF, yF, zero);
      bf16x8 tF = fragc(t);
      f32x4 pz = MFMA(tF, zF, zero);
      #pragma unroll
      for (int r = 0; r < 4; ++r) Zc[r] = 1.5f * Zc[r] - 0.5f * pz[r];
    }

    wv.x = pack2bf(alpha * Zc[0], alpha * Zc[1]);
    wv.y = pack2bf(alpha * Zc[2], alpha * Zc[3]);
  }
  zs[(size_t)pid * 64 + l] = wv;
}

// ---------------- Phase 2: octant apply, f32 direct W ----------------------
// Block = (bi, ci, oc): 4 rows x 64 px = 16 cells. 256 threads, 4 waves.
//   thread t: r = t>>6 (pixel row), px = t&63, cell c = px>>2.
// Gather: wave w4 = t>>6 does cells cc = 4*rd + w4 (4 rounds); per cell
//   4 masked coalesced uint2 zs loads, f32 sum, 1/cnt folded; lane (u,j)
//   writes W[4u+e][j], e=0..3, at pitch 260 f32 (banks 4c%32, 4-lane
//   broadcast per cell -> 2-way = free). 16.6 KB LDS -> 8 blocks/CU.
// Matvec: thread cell c reads 64 broadcast float4, 256 FMA, no unpack.
#define Q_NBLK (NBATCH * NCELL * 8)   // 2048 -> 8 blocks/CU
__global__ __launch_bounds__(256, 8) void llr_ap(const float* __restrict__ x,
                                                 const uint2* __restrict__ zs,
                                                 float* __restrict__ out) {
  __shared__ float PWf[16 * 260];              // 16.6 KB

  const int bid = blockIdx.x;                  // bi*1024 + ci*8 + oc
  const int oc  = bid & 7;
  const int ci  = (bid >> 3) & 127;
  const int bi  = bid >> 10;
  const int t   = threadIdx.x;
  const int r   = t >> 6;                      // pixel row 0..3 (= wave id)
  const int px  = t & 63;                      // pixel col in octant
  const int c   = px >> 2;                     // cell-local 0..15

  const size_t HW = (size_t)HDIM * WDIM;
  const int h   = 4 * ci + r;
  const int wpx = oc * 64 + px;

  // ---- gather: per-cell f32 W -> LDS (4 cells/wave, 4 masked loads each)
  {
    const int w4 = t >> 6;                     // wave 0..3
    const int l  = t & 63;
    const int u  = l >> 4, j = l & 15;
    const uint2* zb = zs + (size_t)bi * NPH * NPW * 64;
    const bool vh0 = (ci > 0), vh1 = (ci < NPH);
    const int ph0c = vh0 ? ci - 1 : 0;
    const int ph1c = vh1 ? ci : NPH - 1;
    const float cnth = 2.0f - (ci == 0) - (ci == NCELL - 1);
    #pragma unroll
    for (int rd = 0; rd < 4; ++rd) {
      const int cc = rd * 4 + w4;              // cell 0..15 (wave-uniform)
      const int cj = oc * 16 + cc;             // global cell col
      const int pwl = cj - 1, pwr = cj;
      const bool vl = (pwl >= 0), vr = (pwr <= NPW - 1);
      const int pwlc = vl ? pwl : 0;
      const int pwrc = vr ? pwr : NPW - 1;
      uint2 z00 = zb[((size_t)ph0c * NPW + pwlc) * 64 + l];
      uint2 z01 = zb[((size_t)ph0c * NPW + pwrc) * 64 + l];
      uint2 z10 = zb[((size_t)ph1c * NPW + pwlc) * 64 + l];
      uint2 z11 = zb[((size_t)ph1c * NPW + pwrc) * 64 + l];
      if (!(vh0 && vl)) { z00.x = 0u; z00.y = 0u; }
      if (!(vh0 && vr)) { z01.x = 0u; z01.y = 0u; }
      if (!(vh1 && vl)) { z10.x = 0u; z10.y = 0u; }
      if (!(vh1 && vr)) { z11.x = 0u; z11.y = 0u; }

      const float cntw = 2.0f - (cj == 0) - (cj == NCELL - 1);
      const float sc = 1.0f / (cnth * cntw);
      float* wb = &PWf[cc * 260 + j];
      wb[16 * (4 * u + 0)] = sc * (blo2f(z00.x) + blo2f(z01.x) + blo2f(z10.x) + blo2f(z11.x));
      wb[16 * (4 * u + 1)] = sc * (bhi2f(z00.x) + bhi2f(z01.x) + bhi2f(z10.x) + bhi2f(z11.x));
      wb[16 * (4 * u + 2)] = sc * (blo2f(z00.y) + blo2f(z01.y) + blo2f(z10.y) + blo2f(z11.y));
      wb[16 * (4 * u + 3)] = sc * (bhi2f(z00.y) + bhi2f(z01.y) + bhi2f(z10.y) + bhi2f(z11.y));
    }
  }
  __syncthreads();

  // ---- phase B: x loads (after barrier), matvec: 64 broadcast float4 reads
  const float* xp = x + (size_t)bi * NCH * HW + (size_t)h * WDIM + wpx;
  float xv[16];
  #pragma unroll
  for (int e = 0; e < 16; ++e) xv[e] = xp[(size_t)e * HW];

  const float* wb = &PWf[c * 260];
  float* po = out + (size_t)bi * NCH * HW + (size_t)h * WDIM + wpx;
  #pragma unroll
  for (int co = 0; co < 16; ++co) {
    float acc = 0.f;
    #pragma unroll
    for (int k = 0; k < 4; ++k) {
      const float4 W4 = *(const float4*)(wb + 16 * co + 4 * k);  // broadcast x4
      acc += W4.x * xv[4 * k + 0];
      acc += W4.y * xv[4 * k + 1];
      acc += W4.z * xv[4 * k + 2];
      acc += W4.w * xv[4 * k + 3];
    }
    po[(size_t)co * HW] = xv[co] - acc;        // scale pre-folded into W
  }
}

extern "C" void kernel_launch(void* const* d_in, const int* in_sizes, int n_in,
                              void* d_out, int out_size, void* d_ws, size_t ws_size,
                              hipStream_t stream) {
  const float* x = (const float*)d_in[0];
  float* out = (float*)d_out;
  uint2* zs = (uint2*)d_ws;                    // 32258*512B = 16.5 MB

  llr_zs<<<dim3(ZS_NBLK), dim3(256), 0, stream>>>(x, zs);
  llr_ap<<<dim3(Q_NBLK), dim3(256), 0, stream>>>(x, zs, out);
}